// Round 3
// baseline (771.853 us; speedup 1.0000x reference)
//
#include <hip/hip_runtime.h>
#include <math.h>

#define B    512
#define L    1024
#define K    8
#define NR   512
#define S    20
#define EXT  26
#define SS   (S*S)            // 400
#define ROWF (K*EXT)          // 208 floats per (b,l)
#define BROW (L*ROWF)         // 212992 floats per b
#define KSTR 840              // per-k stride in XYL workspace: X 400 | Y 400 | lam 20 | pad 20

typedef float f4 __attribute__((ext_vector_type(4)));

__device__ __forceinline__ float softplusf(float x) {
    return fmaxf(x, 0.0f) + log1pf(expf(-fabsf(x)));
}

// wave-local ordering fence: per-wave DS ops complete in order on CDNA, so
// for a wave working on its OWN LDS patch this replaces __syncthreads.
__device__ __forceinline__ void wave_fence() {
    __builtin_amdgcn_wave_barrier();
}

// ---------------------------------------------------------------------------
// Kernel 1: eigendecomposition of the 8 symmetric similarity matrices.
// Q = R diag(pi) is reversible => S = D^{1/2} Q D^{-1/2} is SYMMETRIC
// (S_rc = softplus_rc * sqrt(pi_r pi_c) / mue, S_rr = Q_rr). Jacobi:
// S = U Lam U^T. Then P(tau) = X diag(exp(tau*lam)) Y with
// X = D^{-1/2} U, Y = U^T D^{1/2} -- exact expm, no Taylor, no squarings.
// One block (one wave) per k; parallel cyclic Jacobi: 10 disjoint pairs
// per round (round-robin schedule), 19 rounds/sweep, 8 sweeps.
// All fences wave-local (single wave).
// Output XYL[k*840]: X[400] row-major, Y[400] ([j*20+c]), lam[20].
// ---------------------------------------------------------------------------
__global__ __launch_bounds__(64, 1) void eigen_kernel(
    const float* __restrict__ exch,   // K,S,S
    const float* __restrict__ freq,   // S
    float*       __restrict__ XYL)    // K*840
{
    __shared__ float Am[20*21];       // padded stride 21 (bank-spread)
    __shared__ float Um[20*21];
    __shared__ float sq[20];
    __shared__ float dd[20];
    __shared__ float inv_mue_sh;
    __shared__ float cs_c[10], cs_s[10];
    __shared__ int   pr[10], qr[10];

    const int k    = blockIdx.x;
    const int lane = threadIdx.x;
    const float* E = exch + k * SS;

    if (lane < 20) sq[lane] = sqrtf(freq[lane]);
    wave_fence();

    // build symmetric off-diagonal part (scaled by sq_r*sq_c), U = I
    for (int e = lane; e < 400; e += 64) {
        int r = e / 20, c = e - r*20;
        float v = 0.f;
        if (r != c)
            v = softplusf(0.5f * (E[r*20 + c] + E[c*20 + r])) * sq[r] * sq[c];
        Am[r*21 + c] = v;
        Um[r*21 + c] = (r == c) ? 1.f : 0.f;
    }
    wave_fence();
    // row sums d_r of Q's off-diagonal: A_rc*sq_c = v_rc*sq_r*freq_c
    if (lane < 20) {
        float sacc = 0.f;
        #pragma unroll
        for (int j = 0; j < 20; ++j) sacc += Am[lane*21 + j] * sq[j];
        dd[lane] = sacc / sq[lane];
    }
    wave_fence();
    if (lane == 0) {
        float m = 0.f;
        #pragma unroll
        for (int r = 0; r < 20; ++r) m += sq[r] * sq[r] * dd[r];
        inv_mue_sh = 1.f / fmaxf(m, 1e-16f);
    }
    wave_fence();
    {
        float inv_mue = inv_mue_sh;
        for (int e = lane; e < 400; e += 64) {
            int r = e / 20, c = e - r*20;
            Am[r*21 + c] = (r == c) ? (-dd[r] * inv_mue) : (Am[r*21 + c] * inv_mue);
        }
    }
    wave_fence();

    // ---- parallel cyclic Jacobi: A' = J^T A J, U' = U J ----
    #pragma unroll 1
    for (int sweep = 0; sweep < 8; ++sweep) {
        #pragma unroll 1
        for (int rr = 0; rr < 19; ++rr) {
            if (lane < 10) {
                int p, q;
                if (lane == 0) { p = 19; q = rr; }
                else { p = (rr + lane) % 19; q = (rr + 19 - lane) % 19; }
                float apq = Am[p*21 + q];
                float c = 1.f, s = 0.f;
                if (fabsf(apq) > 1e-25f) {
                    float theta = (Am[q*21 + q] - Am[p*21 + p]) / (2.f * apq);
                    float tt = copysignf(1.f / (fabsf(theta) + sqrtf(theta*theta + 1.f)), theta);
                    c = 1.f / sqrtf(tt*tt + 1.f);
                    s = tt * c;
                }
                cs_c[lane] = c; cs_s[lane] = s; pr[lane] = p; qr[lane] = q;
            }
            wave_fence();
            // phase 1: A row rotations (tasks 0..199) + U column rotations (200..399)
            for (int t4 = lane; t4 < 400; t4 += 64) {
                int m = t4 / 40, rem = t4 - m*40;
                int p = pr[m], q = qr[m];
                float c = cs_c[m], s = cs_s[m];
                if (rem < 20) {
                    int j = rem;
                    float ap = Am[p*21 + j], aq = Am[q*21 + j];
                    Am[p*21 + j] = c*ap - s*aq;
                    Am[q*21 + j] = s*ap + c*aq;
                } else {
                    int i = rem - 20;
                    float up = Um[i*21 + p], uq = Um[i*21 + q];
                    Um[i*21 + p] = c*up - s*uq;
                    Um[i*21 + q] = s*up + c*uq;
                }
            }
            wave_fence();
            // phase 2: A column rotations
            for (int t4 = lane; t4 < 200; t4 += 64) {
                int m = t4 / 20, i = t4 - m*20;
                int p = pr[m], q = qr[m];
                float c = cs_c[m], s = cs_s[m];
                float ap = Am[i*21 + p], aq = Am[i*21 + q];
                Am[i*21 + p] = c*ap - s*aq;
                Am[i*21 + q] = s*ap + c*aq;
            }
            wave_fence();
        }
    }

    // ---- output: X = D^{-1/2} U, Y = U^T D^{1/2}, lam = diag(A) ----
    float* O = XYL + k * KSTR;
    for (int e = lane; e < KSTR; e += 64) {
        float v = 0.f;
        if (e < 400) {
            int r = e / 20, c = e - r*20;
            v = Um[r*21 + c] / sq[r];
        } else if (e < 800) {
            int i = e - 400; int j = i / 20, c = i - j*20;
            v = Um[c*21 + j] * sq[c];
        } else if (e < 820) {
            int j = e - 800;
            v = Am[j*21 + j];
        }
        O[e] = v;
    }
}

// ---------------------------------------------------------------------------
// Kernel 2: fused per-b. Block = one b (512 blocks, 512 threads = 8 waves,
// 2 blocks/CU). Wave w builds P for matrix k=w via ONE 20x20x20 matmul:
//   P = X * diag(exp(tau*lam)) * Y
// with Y-column-slices (scaled by e_j) stationary in regs, X rows read from
// LDS as float4 (rows are 16B-aligned: 20 floats * 4B = 80B). Then the
// Row-LUT build + streaming store are VERBATIM the verified 478us kernel.
// LDS: Xs 12.8K + Ys 12.8K + lam 0.6K + Row 21.6K + inp 4K = 52KB.
// ---------------------------------------------------------------------------
__global__ __launch_bounds__(512, 2) void fused2_kernel(
    const int*   __restrict__ inputs,        // B,L
    const int*   __restrict__ rate_indices,  // B
    const float* __restrict__ tau_kernel,    // NR
    const float* __restrict__ XYL,           // K*840
    float*       __restrict__ out)           // B,L,208
{
    __shared__ __align__(16) float Xs[K][400];
    __shared__ float Ys[K][400];
    __shared__ float lam_sh[K][20];
    __shared__ __align__(16) float Row[EXT*ROWF];   // 21632 B
    __shared__ int inp_sh[L];                       // 4096 B

    const int b    = blockIdx.x;
    const int t    = threadIdx.x;
    const int w    = t >> 6;          // wave id == matrix k
    const int lane = t & 63;
    const int li = lane >> 3, lj = lane & 7;
    const int r0 = 3*li, c0 = 3*lj;   // 3x3 tile origin in 24x24 grid over 20x20

    // ---- phase 0 ----
    for (int u = t; u < L; u += 512) inp_sh[u] = inputs[b*L + u];
    for (int e = t; e < EXT*ROWF; e += 512) {
        int row = e / ROWF, c = e - row*ROWF;
        int kk = c / EXT, s = c - kk*EXT;
        (void)kk;
        if (row < S) {
            if (s >= S) Row[e] = 0.f;              // pad cols only; P cells skipped
        } else {
            Row[e] = (s == row) ? 1.f : 0.f;       // one-hot rows
        }
    }
    // stage X/Y/lam for all 8 k's (coalesced)
    for (int e = t; e < K*KSTR; e += 512) {
        int k = e / KSTR, rem = e - k*KSTR;
        float v = XYL[e];
        if (rem < 400)      Xs[k][rem] = v;
        else if (rem < 800) Ys[k][rem - 400] = v;
        else if (rem < 820) lam_sh[k][rem - 800] = v;
    }
    float tau = softplusf(tau_kernel[rate_indices[b]]);
    __syncthreads();   // staged by all threads, consumed per-wave

    // ---- per-wave: Ye[j][dc] = exp(tau*lam_j) * Y[j][c0+dc] (stationary) ----
    float Ye[S][3];
    #pragma unroll
    for (int j = 0; j < S; ++j) {
        float ej = __expf(tau * lam_sh[w][j]);
        #pragma unroll
        for (int dc = 0; dc < 3; ++dc) {
            int c = c0 + dc;
            Ye[j][dc] = (c < S) ? ej * Ys[w][j*20 + c] : 0.f;
        }
    }

    // ---- ONE matmul: C = Xrows * Ye ----
    float C[3][3] = {{0.f,0.f,0.f},{0.f,0.f,0.f},{0.f,0.f,0.f}};
    {
        const float* Xw = &Xs[w][0];
        const bool v0 = (r0 + 0) < S;
        const bool v1 = (r0 + 1) < S;
        const bool v2 = (r0 + 2) < S;
        #pragma unroll
        for (int jc = 0; jc < 5; ++jc) {
            float4 a0 = v0 ? *(const float4*)&Xw[(r0+0)*20 + 4*jc] : make_float4(0,0,0,0);
            float4 a1 = v1 ? *(const float4*)&Xw[(r0+1)*20 + 4*jc] : make_float4(0,0,0,0);
            float4 a2 = v2 ? *(const float4*)&Xw[(r0+2)*20 + 4*jc] : make_float4(0,0,0,0);
            float t0[4] = {a0.x, a0.y, a0.z, a0.w};
            float t1[4] = {a1.x, a1.y, a1.z, a1.w};
            float t2[4] = {a2.x, a2.y, a2.z, a2.w};
            #pragma unroll
            for (int dj = 0; dj < 4; ++dj) {
                int j = 4*jc + dj;
                #pragma unroll
                for (int dc = 0; dc < 3; ++dc) {
                    C[0][dc] = fmaf(t0[dj], Ye[j][dc], C[0][dc]);
                    C[1][dc] = fmaf(t1[dj], Ye[j][dc], C[1][dc]);
                    C[2][dc] = fmaf(t2[dj], Ye[j][dc], C[2][dc]);
                }
            }
        }
    }

    // ---- P tiles -> Row LUT (only r<20, c<20 cells; disjoint from init) ----
    #pragma unroll
    for (int dr = 0; dr < 3; ++dr) {
        int r = r0 + dr; if (r >= S) continue;
        #pragma unroll
        for (int dc = 0; dc < 3; ++dc) {
            int c = c0 + dc; if (c >= S) continue;
            Row[r*ROWF + w*EXT + c] = C[dr][dc];
        }
    }
    __syncthreads();   // the only other block-wide barrier

    // ---- streaming store: VERBATIM the verified 478us kernel ----
    int l0[13], qq[13];
    {
        int uu = t;
        #pragma unroll
        for (int j = 0; j < 13; ++j) {
            l0[j] = uu / 52;
            qq[j] = uu - l0[j] * 52;
            uu += 512;
        }
    }
    const f4* Row4 = (const f4*)Row;
    f4* out4 = (f4*)out + (size_t)b * (BROW/4);
    #pragma unroll 1
    for (int i = 0; i < 8; ++i) {
        int lbase = i << 7;          // 128*i
        int ubase = t + i * 6656;
        #pragma unroll
        for (int j = 0; j < 13; ++j) {
            int inp = inp_sh[l0[j] + lbase];
            out4[ubase + (j << 9)] = Row4[inp * 52 + qq[j]];
        }
    }
}

// ---------------------------------------------------------------------------
extern "C" void kernel_launch(void* const* d_in, const int* in_sizes, int n_in,
                              void* d_out, int out_size, void* d_ws, size_t ws_size,
                              hipStream_t stream) {
    const int*   inputs  = (const int*)  d_in[0];  // (B,L) int32
    const int*   rate_ix = (const int*)  d_in[1];  // (B,) int32
    const float* tau_k   = (const float*)d_in[2];  // (NR,) f32
    const float* exch    = (const float*)d_in[3];  // (K,S,S) f32
    const float* freq    = (const float*)d_in[4];  // (S,) f32
    float* out = (float*)d_out;
    float* xyl = (float*)d_ws;                     // needs 8*840*4 = 26880 B

    (void)in_sizes; (void)n_in; (void)out_size; (void)ws_size;

    eigen_kernel<<<K, 64, 0, stream>>>(exch, freq, xyl);
    fused2_kernel<<<B, 512, 0, stream>>>(inputs, rate_ix, tau_k, xyl, out);
}

// Round 5
// 484.072 us; speedup vs baseline: 1.5945x; 1.5945x over previous
//
#include <hip/hip_runtime.h>
#include <math.h>

#define B    512
#define L    1024
#define K    8
#define NR   512
#define S    20
#define EXT  26
#define SS   (S*S)            // 400
#define PD   24               // padded matrix dim (zero pad is matmul-self-consistent)
#define PDSQ (PD*PD)          // 576
#define ROWF (K*EXT)          // 208 floats per (b,l)
#define BROW (L*ROWF)         // 212992 floats per b

typedef float f4 __attribute__((ext_vector_type(4)));

__device__ __forceinline__ float softplusf(float x) {
    return fmaxf(x, 0.0f) + log1pf(expf(-fabsf(x)));
}

// wave-local ordering fence: per-wave DS ops complete in order on CDNA, so
// for a wave working on its OWN LDS patch this replaces __syncthreads.
__device__ __forceinline__ void wave_fence() {
    __builtin_amdgcn_wave_barrier();
}

// ---------------------------------------------------------------------------
// ONE fused kernel (round-0 verified structure). Block = one b (512 blocks,
// 512 threads = 8 waves, 2 blocks/CU). Wave w owns matrix k=w in LDS.
//   Phase 0/1: identical to the 478us-verified kernel (Taylor expm).
//   Phase 2 CHANGED: store mapping u = i*6656 + w*832 + j*64 + lane so each
//   wave's 13 consecutive stores cover a CONTIGUOUS 13KB range in order
//   (was 8KB-strided 1KB bursts -> HBM row-buffer misses, ~2.6 TB/s).
//   832 = 13*64 and 52|832, so (l,q) stays j-periodic and division-free.
// ---------------------------------------------------------------------------
__global__ __launch_bounds__(512, 2) void fused_kernel(
    const int*   __restrict__ inputs,        // B,L
    const int*   __restrict__ rate_indices,  // B
    const float* __restrict__ tau_kernel,    // NR
    const float* __restrict__ exch,          // K,S,S
    const float* __restrict__ freq,          // S
    float* __restrict__ out)                 // B,L,208
{
    __shared__ __align__(16) float M[K][2][PDSQ];   // 36864 B
    __shared__ __align__(16) float Row[EXT*ROWF];   // 21632 B
    __shared__ int   inp_sh[L];                     // 4096 B
    __shared__ float diag_sh[K][S];
    __shared__ float mue_sh[K];

    const int b    = blockIdx.x;
    const int t    = threadIdx.x;
    const int w    = t >> 6;          // wave id == matrix k
    const int lane = t & 63;
    const int li = lane >> 3, lj = lane & 7;
    const int r0 = 3*li, c0 = 3*lj;   // 3x3 tile origin in 24x24

    // ---- phase 0 (no cross-wave ordering needed until the final barrier) ----
    for (int u = t; u < L; u += 512) inp_sh[u] = inputs[b*L + u];
    for (int e = t; e < EXT*ROWF; e += 512) {
        int row = e / ROWF, c = e - row*ROWF;
        int k = c / EXT, s = c - k*EXT;
        (void)k;
        if (row < S) {
            if (s >= S) Row[e] = 0.f;              // pad cols only; P cells skipped
        } else {
            Row[e] = (s == row) ? 1.f : 0.f;       // one-hot rows
        }
    }
    float* M0 = &M[w][0][0];
    float* M1 = &M[w][1][0];
    for (int e = lane; e < 2*PDSQ; e += 64) M0[e] = 0.f;  // zero both buffers
    // tau: uniform loads, computed redundantly in every lane
    float tau = softplusf(tau_kernel[rate_indices[b]]);
    wave_fence();

    // ---- phase 1: build A = (Q_w / mue) * tau / 2^6 in M0 ----
    const float* E = exch + w * SS;
    for (int e = lane; e < SS; e += 64) {
        int r = e / S, c = e - r*S;
        float v = 0.f;
        if (r != c)
            v = softplusf(0.5f * (E[r*S + c] + E[c*S + r])) * freq[c];
        M0[r*PD + c] = v;
    }
    wave_fence();
    if (lane < S) {
        float d = 0.f;
        #pragma unroll
        for (int j = 0; j < S; ++j) d += M0[lane*PD + j];
        diag_sh[w][lane] = d;
    }
    wave_fence();
    if (lane == 0) {
        float m = 0.f;
        #pragma unroll
        for (int s = 0; s < S; ++s) m += freq[s] * diag_sh[w][s];
        mue_sh[w] = fmaxf(m, 1e-16f);
    }
    wave_fence();
    {
        float scale = tau * 0.015625f;
        float mue   = mue_sh[w];
        for (int e = lane; e < SS; e += 64) {
            int r = e / S, c = e - r*S;
            float v = (r == c) ? -diag_sh[w][r] : M0[r*PD + c];
            M0[r*PD + c] = (v / mue) * scale;
        }
    }
    wave_fence();

    // ---- expm: A cols in regs, P=I+A, order-10 Taylor, 6 squarings ----
    float Ac[S][3];
    #pragma unroll
    for (int j = 0; j < S; ++j) {
        #pragma unroll
        for (int d = 0; d < 3; ++d)
            Ac[j][d] = M0[j*PD + c0 + d];
    }

    float P[3][3];
    #pragma unroll
    for (int dr = 0; dr < 3; ++dr)
        #pragma unroll
        for (int dc = 0; dc < 3; ++dc) {
            int r = r0 + dr, c = c0 + dc;
            P[dr][dc] = M0[r*PD + c] + ((r == c && r < S) ? 1.f : 0.f);
        }

    const float* Tc = M0;
    float* Tn = M1;
    #pragma unroll 1
    for (int i = 2; i <= 10; ++i) {
        float C[3][3] = {{0.f,0.f,0.f},{0.f,0.f,0.f},{0.f,0.f,0.f}};
        #pragma unroll
        for (int jc = 0; jc < 5; ++jc) {
            float4 a0 = *(const float4*)&Tc[(r0+0)*PD + 4*jc];
            float4 a1 = *(const float4*)&Tc[(r0+1)*PD + 4*jc];
            float4 a2 = *(const float4*)&Tc[(r0+2)*PD + 4*jc];
            float t0[4] = {a0.x, a0.y, a0.z, a0.w};
            float t1[4] = {a1.x, a1.y, a1.z, a1.w};
            float t2[4] = {a2.x, a2.y, a2.z, a2.w};
            #pragma unroll
            for (int dj = 0; dj < 4; ++dj) {
                int j = 4*jc + dj;
                #pragma unroll
                for (int dc = 0; dc < 3; ++dc) {
                    C[0][dc] = fmaf(t0[dj], Ac[j][dc], C[0][dc]);
                    C[1][dc] = fmaf(t1[dj], Ac[j][dc], C[1][dc]);
                    C[2][dc] = fmaf(t2[dj], Ac[j][dc], C[2][dc]);
                }
            }
        }
        float inv = 1.0f / (float)i;
        #pragma unroll
        for (int dr = 0; dr < 3; ++dr)
            #pragma unroll
            for (int dc = 0; dc < 3; ++dc) {
                C[dr][dc] *= inv;
                P[dr][dc] += C[dr][dc];
                Tn[(r0+dr)*PD + c0 + dc] = C[dr][dc];
            }
        wave_fence();
        float* tmp = (float*)Tc; Tc = Tn; Tn = tmp;
    }

    #pragma unroll 1
    for (int sq = 0; sq < 6; ++sq) {
        #pragma unroll
        for (int dr = 0; dr < 3; ++dr)
            #pragma unroll
            for (int dc = 0; dc < 3; ++dc)
                Tn[(r0+dr)*PD + c0 + dc] = P[dr][dc];
        wave_fence();
        const float* Pb = Tn;
        float C[3][3] = {{0.f,0.f,0.f},{0.f,0.f,0.f},{0.f,0.f,0.f}};
        #pragma unroll
        for (int jc = 0; jc < 5; ++jc) {
            float4 a0 = *(const float4*)&Pb[(r0+0)*PD + 4*jc];
            float4 a1 = *(const float4*)&Pb[(r0+1)*PD + 4*jc];
            float4 a2 = *(const float4*)&Pb[(r0+2)*PD + 4*jc];
            float t0[4] = {a0.x, a0.y, a0.z, a0.w};
            float t1[4] = {a1.x, a1.y, a1.z, a1.w};
            float t2[4] = {a2.x, a2.y, a2.z, a2.w};
            float cb[4][3];
            #pragma unroll
            for (int dj = 0; dj < 4; ++dj)
                #pragma unroll
                for (int dc = 0; dc < 3; ++dc)
                    cb[dj][dc] = Pb[(4*jc + dj)*PD + c0 + dc];
            #pragma unroll
            for (int dj = 0; dj < 4; ++dj)
                #pragma unroll
                for (int dc = 0; dc < 3; ++dc) {
                    C[0][dc] = fmaf(t0[dj], cb[dj][dc], C[0][dc]);
                    C[1][dc] = fmaf(t1[dj], cb[dj][dc], C[1][dc]);
                    C[2][dc] = fmaf(t2[dj], cb[dj][dc], C[2][dc]);
                }
        }
        #pragma unroll
        for (int dr = 0; dr < 3; ++dr)
            #pragma unroll
            for (int dc = 0; dc < 3; ++dc)
                P[dr][dc] = C[dr][dc];
        float* tmp = (float*)Tc; Tc = Tn; Tn = tmp;
        wave_fence();
    }

    // ---- P tiles -> Row LUT (only r<20, c<20 cells; disjoint from init) ----
    #pragma unroll
    for (int dr = 0; dr < 3; ++dr) {
        int r = r0 + dr; if (r >= S) continue;
        #pragma unroll
        for (int dc = 0; dc < 3; ++dc) {
            int c = c0 + dc; if (c >= S) continue;
            Row[r*ROWF + w*EXT + c] = P[dr][dc];
        }
    }
    __syncthreads();   // the ONLY block-wide barrier

    // ---- phase 2: wave-contiguous streaming store ----
    // u = i*6656 + w*832 + j*64 + lane  (i<8, w<8, j<13, lane<64) — bijective
    // onto [0, 53248). Wave's 13 stores are CONTIGUOUS 13KB in order (HBM
    // row-buffer friendly). 832 = 16*52 and 6656 = 128*52, so
    // l = i*128 + w*16 + (64j+lane)/52 and q = (64j+lane)%52: division-free,
    // j-periodic per thread.
    int d13[13], qq[13];
    {
        int uu = lane;
        #pragma unroll
        for (int j = 0; j < 13; ++j) {
            d13[j] = uu / 52;
            qq[j] = uu - d13[j] * 52;
            uu += 64;
        }
    }
    const f4* Row4 = (const f4*)Row;
    f4* out4 = (f4*)out + (size_t)b * (BROW/4);
    #pragma unroll 1
    for (int i = 0; i < 8; ++i) {
        int lidx  = (i << 7) + (w << 4);      // i*128 + w*16
        int ubase = i * 6656 + w * 832 + lane;
        #pragma unroll
        for (int j = 0; j < 13; ++j) {
            int inp = inp_sh[lidx + d13[j]];
            out4[ubase + (j << 6)] = Row4[inp * 52 + qq[j]];
        }
    }
}

// ---------------------------------------------------------------------------
extern "C" void kernel_launch(void* const* d_in, const int* in_sizes, int n_in,
                              void* d_out, int out_size, void* d_ws, size_t ws_size,
                              hipStream_t stream) {
    const int*   inputs  = (const int*)  d_in[0];  // (B,L) int32
    const int*   rate_ix = (const int*)  d_in[1];  // (B,) int32
    const float* tau_k   = (const float*)d_in[2];  // (NR,) f32
    const float* exch    = (const float*)d_in[3];  // (K,S,S) f32
    const float* freq    = (const float*)d_in[4];  // (S,) f32
    float* out = (float*)d_out;

    (void)d_ws; (void)ws_size; (void)in_sizes; (void)n_in; (void)out_size;

    fused_kernel<<<B, 512, 0, stream>>>(inputs, rate_ix, tau_k, exch, freq, out);
}